// Round 8
// baseline (201.651 us; speedup 1.0000x reference)
//
#include <hip/hip_runtime.h>
#include <math.h>

// Problem shape (from reference setup_inputs): B=4096, D=2048, C=1000, N=C+B=5096.
#define D_DIM 2048
// |approx_logit - exact_logit| bound: fp16-MFMA dot (~0.013) + 4x f16 partial
// roundings (~0.008). Candidate containment needs GAP_TAU >= true bound.
#define GAP_TAU 0.035f
#define SPLITK 4

typedef _Float16 f16;
typedef f16 f16x8 __attribute__((ext_vector_type(8)));
typedef f16 f16x4 __attribute__((ext_vector_type(4)));
typedef float f32x4 __attribute__((ext_vector_type(4)));

__device__ __forceinline__ const float* support_row(int i, const float* __restrict__ W,
                                                    const float* __restrict__ z, int C) {
  return (i < C) ? (W + (size_t)i * D_DIM) : (z + (size_t)(i - C) * D_DIM);
}

// async global->LDS, 16B per lane. LDS dest = wave-uniform base + lane*16.
__device__ __forceinline__ void async_ld16(const f16* g, f16* l) {
  __builtin_amdgcn_global_load_lds((const __attribute__((address_space(1))) void*)g,
                                   (__attribute__((address_space(3))) void*)l, 16, 0, 0);
}

// ---------------------------------------------------------------------------
// prep: suph[i][:] = f16(support_row(i)) (zeros for pad rows); norms[i] = ||row||.
// One wave per row (4 rows/block), shuffle-only reduction.
// ---------------------------------------------------------------------------
__global__ __launch_bounds__(256) void prep_kernel(const float* __restrict__ z,
                                                   const float* __restrict__ W,
                                                   int C, int Nsup,
                                                   f16* __restrict__ suph,
                                                   float* __restrict__ norms) {
  const int wave = threadIdx.x >> 6;
  const int lane = threadIdx.x & 63;
  const int i = blockIdx.x * 4 + wave;
  f16* dst = suph + (size_t)i * D_DIM;
  if (i >= Nsup) {
    f16x8 zz = {0, 0, 0, 0, 0, 0, 0, 0};
#pragma unroll
    for (int p = 0; p < 4; p++) *(f16x8*)(dst + p * 512 + lane * 8) = zz;
    return;
  }
  const float* src = support_row(i, W, z, C);
  float ss = 0.f;
#pragma unroll
  for (int p = 0; p < 4; p++) {
    const int off = p * 512 + lane * 8;
    const float4 a = *(const float4*)(src + off);
    const float4 b = *(const float4*)(src + off + 4);
    f16x8 v;
    v[0] = (f16)a.x; v[1] = (f16)a.y; v[2] = (f16)a.z; v[3] = (f16)a.w;
    v[4] = (f16)b.x; v[5] = (f16)b.y; v[6] = (f16)b.z; v[7] = (f16)b.w;
    *(f16x8*)(dst + off) = v;
    ss = fmaf(a.x, a.x, ss); ss = fmaf(a.y, a.y, ss);
    ss = fmaf(a.z, a.z, ss); ss = fmaf(a.w, a.w, ss);
    ss = fmaf(b.x, b.x, ss); ss = fmaf(b.y, b.y, ss);
    ss = fmaf(b.z, b.z, ss); ss = fmaf(b.w, b.w, ss);
  }
#pragma unroll
  for (int s = 1; s < 64; s <<= 1) ss += __shfl_xor(ss, s);
  if (lane == 0) norms[i] = sqrtf(ss);
}

// ---------------------------------------------------------------------------
// fp16 MFMA GEMM, split-K=4 via blockIdx.z, f16 partials (same HBM bytes as
// split-2 fp32): P[kz] = f16(A[:, kz*Ks:(kz+1)*Ks] @ B^T). 128x128 tile,
// BK=32, 256 thr = 4 waves (2x2), wave = 64x64 = 4x4 MFMA 16x16x32.
// global_load_lds width=16 staging; 16B-chunk XOR swizzle key (row>>1)&3
// (conflict-free). A/B padded to x128 rows; stores unpredicated into padded
// partial buffers. GEMM1: 1280 blocks (5.0/CU even); GEMM2: 1024 (4.0/CU).
// ---------------------------------------------------------------------------
#define TM 128
#define TN 128

__global__ __launch_bounds__(256) void gemm_f16(const f16* __restrict__ A,
                                                const f16* __restrict__ B,
                                                f16* __restrict__ P,
                                                int K, int Ks, long partStride, int ldc) {
  __shared__ __align__(16) f16 As[TM * 32];
  __shared__ __align__(16) f16 Bs[TN * 32];

  const int tid = threadIdx.x;
  const int wave = tid >> 6;
  const int lane = tid & 63;
  const int quad = lane >> 4;
  const int lr = lane & 15;
  const int row0 = blockIdx.x * TM;
  const int col0 = blockIdx.y * TN;
  const int kz = blockIdx.z;
  const int kbase = kz * Ks;
  const int wr = (wave >> 1) * 64;
  const int wc = (wave & 1) * 64;

  const f16* ag[2];
  const f16* bg[2];
  f16* al[2];
  f16* bl[2];
#pragma unroll
  for (int s = 0; s < 2; s++) {
    const int i = (wave * 2 + s) * 64 + lane;   // == LDS chunk id (staging contract)
    const int row = i >> 2;
    const int cg = (i & 3) ^ ((row >> 1) & 3);
    ag[s] = A + (size_t)(row0 + row) * K + kbase + cg * 8;
    bg[s] = B + (size_t)(col0 + row) * K + kbase + cg * 8;
    al[s] = As + (wave * 2 + s) * 512;
    bl[s] = Bs + (wave * 2 + s) * 512;
  }

  int aoff[4], boff[4];
#pragma unroll
  for (int tq = 0; tq < 4; tq++) {
    const int ra = wr + tq * 16 + lr;
    aoff[tq] = ra * 32 + (quad ^ ((ra >> 1) & 3)) * 8;
    const int rb = wc + tq * 16 + lr;
    boff[tq] = rb * 32 + (quad ^ ((rb >> 1) & 3)) * 8;
  }

  f32x4 acc[4][4];
#pragma unroll
  for (int i = 0; i < 4; i++)
#pragma unroll
    for (int j = 0; j < 4; j++) {
      acc[i][j][0] = 0.f; acc[i][j][1] = 0.f; acc[i][j][2] = 0.f; acc[i][j][3] = 0.f;
    }

  for (int k0 = 0; k0 < Ks; k0 += 32) {
#pragma unroll
    for (int s = 0; s < 2; s++) {
      async_ld16(ag[s] + k0, al[s]);
      async_ld16(bg[s] + k0, bl[s]);
    }
    __syncthreads();

    f16x8 af[4], bf[4];
#pragma unroll
    for (int i = 0; i < 4; i++) af[i] = *(const f16x8*)(As + aoff[i]);
#pragma unroll
    for (int i = 0; i < 4; i++) bf[i] = *(const f16x8*)(Bs + boff[i]);
#pragma unroll
    for (int i = 0; i < 4; i++)
#pragma unroll
      for (int j = 0; j < 4; j++)
        acc[i][j] = __builtin_amdgcn_mfma_f32_16x16x32_f16(af[i], bf[j], acc[i][j], 0, 0, 0);
    __syncthreads();
  }

  f16* out = P + (size_t)kz * partStride;
#pragma unroll
  for (int i = 0; i < 4; i++)
#pragma unroll
    for (int reg = 0; reg < 4; reg++) {
      const int r = row0 + wr + i * 16 + quad * 4 + reg;
#pragma unroll
      for (int j = 0; j < 4; j++) {
        const int c = col0 + wc + j * 16 + lr;
        out[(size_t)r * ldc + c] = (f16)acc[i][j][reg];
      }
    }
}

// ---------------------------------------------------------------------------
// row_stats (block-per-row): logits row = sum of 4 f16 partials, read as one
// coalesced f16x4 (8B) per partial per thread (thread t owns cols t*4..+3).
// Argmax (lowest-index ties) + top-2 gap + entropy; ambiguous rows
// (gap <= 2*TAU) repaired with exact fp32 dots over candidate classes.
// ---------------------------------------------------------------------------
__global__ __launch_bounds__(256) void row_stats(const f16* __restrict__ P,
                                                 long partStride, int ldp, int Cc,
                                                 const float* __restrict__ z,
                                                 const float* __restrict__ W,
                                                 float* __restrict__ ent,
                                                 int* __restrict__ yhat) {
  const int r = blockIdx.x;
  const int t = threadIdx.x;
  const int wave = t >> 6;
  const int lane = t & 63;
  const int c0 = t * 4;

  float v[4] = {0.f, 0.f, 0.f, 0.f};
#pragma unroll
  for (int kz = 0; kz < SPLITK; kz++) {
    const f16x4 p = *(const f16x4*)(P + (size_t)kz * partStride + (size_t)r * ldp + c0);
#pragma unroll
    for (int k = 0; k < 4; k++) v[k] += (float)p[k];
  }
#pragma unroll
  for (int k = 0; k < 4; k++)
    if (c0 + k >= Cc) v[k] = -3.0e38f;

  // per-thread top-2 (+ lowest argmax idx; ascending k -> first hit wins)
  float m1 = -3.0e38f, m2 = -3.0e38f;
  int i1 = 0x7fffffff;
#pragma unroll
  for (int k = 0; k < 4; k++) {
    if (v[k] > m1) { m2 = m1; m1 = v[k]; i1 = c0 + k; }
    else if (v[k] > m2) { m2 = v[k]; }   // v[k]==m1 lands here -> m2=m1 (gap 0)
  }
  // wave merge
#pragma unroll
  for (int s = 1; s < 64; s <<= 1) {
    const float om1 = __shfl_xor(m1, s);
    const float om2 = __shfl_xor(m2, s);
    const int oi1 = __shfl_xor(i1, s);
    if (om1 > m1) { m2 = fmaxf(m1, om2); m1 = om1; i1 = oi1; }
    else if (om1 < m1) { m2 = fmaxf(m2, om1); }
    else { i1 = min(i1, oi1); m2 = m1; }
  }
  // cross-wave merge via LDS
  __shared__ float sm1[4], sm2[4];
  __shared__ int si[4];
  __shared__ float bc[4];   // M1, M2, S1, S2
  __shared__ int bidx;
  if (lane == 0) { sm1[wave] = m1; sm2[wave] = m2; si[wave] = i1; }
  __syncthreads();
  if (t == 0) {
    float M1 = sm1[0], M2 = sm2[0];
    int I = si[0];
#pragma unroll
    for (int w = 1; w < 4; w++) {
      const float o1 = sm1[w], o2 = sm2[w];
      const int oi = si[w];
      if (o1 > M1) { M2 = fmaxf(M1, o2); M1 = o1; I = oi; }
      else if (o1 < M1) { M2 = fmaxf(M2, o1); }
      else { I = min(I, oi); M2 = M1; }
    }
    bc[0] = M1; bc[1] = M2; bidx = I;
  }
  __syncthreads();
  const float M1 = bc[0];
  const float M2 = bc[1];
  int I1 = bidx;

  // entropy sums rel. M1 (consumed only if a class exceeds K members)
  float s1 = 0.f, s2 = 0.f;
#pragma unroll
  for (int k = 0; k < 4; k++) {
    if (c0 + k < Cc) {
      const float d = v[k] - M1;
      const float e = __expf(d);
      s1 += e;
      s2 = fmaf(d, e, s2);
    }
  }
#pragma unroll
  for (int s = 1; s < 64; s <<= 1) {
    s1 += __shfl_xor(s1, s);
    s2 += __shfl_xor(s2, s);
  }
  if (lane == 0) { sm1[wave] = s1; sm2[wave] = s2; }
  __syncthreads();
  if (t == 0) {
    bc[2] = sm1[0] + sm1[1] + sm1[2] + sm1[3];
    bc[3] = sm2[0] + sm2[1] + sm2[2] + sm2[3];
  }

  // ambiguous-argmax repair with exact fp32 dots (~11% of rows at tau=0.035)
  if (M1 - M2 <= 2.0f * GAP_TAU) {
    __shared__ int cand[64];
    __shared__ int ncand;
    __shared__ float red[256];
    if (t == 0) ncand = 0;
    __syncthreads();
    const float thresh = M1 - 2.0f * GAP_TAU;
#pragma unroll
    for (int k = 0; k < 4; k++) {
      if (c0 + k < Cc && v[k] >= thresh) {
        const int p = atomicAdd(&ncand, 1);
        if (p < 64) cand[p] = c0 + k;
      }
    }
    __syncthreads();
    const bool overflow = (ncand > 64);
    const int nc = overflow ? Cc : ncand;
    const float* srow = support_row(r, W, z, Cc);
    float best = -3.0e38f;
    int bi = 0x7fffffff;
    for (int j = 0; j < nc; j++) {
      const int c = overflow ? j : cand[j];
      const float* wrow = W + (size_t)c * D_DIM;
      float s = 0.f;
      for (int d = t; d < D_DIM; d += 256) s = fmaf(srow[d], wrow[d], s);
      red[t] = s;
      __syncthreads();
      for (int k = 128; k > 0; k >>= 1) {
        if (t < k) red[t] += red[t + k];
        __syncthreads();
      }
      const float val = red[0];
      __syncthreads();
      if (val > best || (val == best && c < bi)) { best = val; bi = c; }
    }
    I1 = bi;
  }
  __syncthreads();

  if (t == 0) {
    const float S1 = bc[2], S2 = bc[3];
    ent[r] = logf(S1) - S2 / S1;
    yhat[r] = I1;
  }
}

// ---------------------------------------------------------------------------
// accum: per class — gather members into LDS, top-K by entropy if count > K
// (never in practice: mean ~5, K=100), sum normalized rows, column-normalize,
// write f16 weights row. Pad classes write zeros. Thread t owns dims t*8..+7.
// ---------------------------------------------------------------------------
#define MAXLIST 1024

__global__ __launch_bounds__(256) void accum_kernel(const float* __restrict__ z,
                                                    const float* __restrict__ W,
                                                    int C, int Nsup,
                                                    const int* __restrict__ yhat,
                                                    const float* __restrict__ ent,
                                                    const float* __restrict__ norms,
                                                    const int* __restrict__ Kp,
                                                    f16* __restrict__ wh) {
  const int c = blockIdx.x;
  const int t = threadIdx.x;
  f16* dst = wh + (size_t)c * D_DIM + t * 8;
  if (c >= C) {
    f16x8 zz = {0, 0, 0, 0, 0, 0, 0, 0};
    *(f16x8*)dst = zz;
    return;
  }

  __shared__ int list[MAXLIST];
  __shared__ unsigned char sel[MAXLIST];
  __shared__ int cnt;
  __shared__ float red[256];
  if (t == 0) cnt = 0;
  __syncthreads();
  for (int i = t; i < Nsup; i += 256) {
    if (yhat[i] == c) {
      const int p = atomicAdd(&cnt, 1);
      if (p < MAXLIST) list[p] = i;
    }
  }
  __syncthreads();
  const int K = *Kp;
  const int n = min(cnt, MAXLIST);
  if (cnt <= K) {
    for (int j = t; j < n; j += 256) sel[j] = 1;
  } else {
    for (int j = t; j < n; j += 256) {
      const int si = list[j];
      const float ei = ent[si];
      int rank = 0;
      for (int l = 0; l < n; l++) {
        const int sl = list[l];
        const float el = ent[sl];
        rank += (el < ei || (el == ei && sl < si)) ? 1 : 0;
      }
      sel[j] = (rank < K) ? 1 : 0;
    }
  }
  __syncthreads();

  float a[8];
#pragma unroll
  for (int q = 0; q < 8; q++) a[q] = 0.f;
  for (int j = 0; j < n; j++) {
    if (!sel[j]) continue;
    const int si = list[j];
    const float* row = support_row(si, W, z, C) + t * 8;
    const float inv = 1.0f / fmaxf(norms[si], 1e-12f);
    const float4 p0 = *(const float4*)row;
    const float4 p1 = *(const float4*)(row + 4);
    a[0] = fmaf(p0.x, inv, a[0]); a[1] = fmaf(p0.y, inv, a[1]);
    a[2] = fmaf(p0.z, inv, a[2]); a[3] = fmaf(p0.w, inv, a[3]);
    a[4] = fmaf(p1.x, inv, a[4]); a[5] = fmaf(p1.y, inv, a[5]);
    a[6] = fmaf(p1.z, inv, a[6]); a[7] = fmaf(p1.w, inv, a[7]);
  }

  float ss = 0.f;
#pragma unroll
  for (int q = 0; q < 8; q++) ss = fmaf(a[q], a[q], ss);
  red[t] = ss;
  __syncthreads();
  for (int k = 128; k > 0; k >>= 1) {
    if (t < k) red[t] += red[t + k];
    __syncthreads();
  }
  const float invn = 1.0f / fmaxf(sqrtf(red[0]), 1e-12f);
  f16x8 o;
#pragma unroll
  for (int q = 0; q < 8; q++) o[q] = (f16)(a[q] * invn);
  *(f16x8*)dst = o;
}

// ---------------------------------------------------------------------------
// reduce_out: out[r][c] = sum of 4 f16 partials, c < Ncols. One block per
// row; thread t owns cols t*4..t*4+3 (coalesced f16x4 loads, float4 store).
// ---------------------------------------------------------------------------
__global__ __launch_bounds__(256) void reduce_out(const f16* __restrict__ Q,
                                                  long partStride, int ldq,
                                                  float* __restrict__ out, int Ncols) {
  const int r = blockIdx.x;
  const int c0 = threadIdx.x * 4;
  float v[4] = {0.f, 0.f, 0.f, 0.f};
#pragma unroll
  for (int kz = 0; kz < SPLITK; kz++) {
    const f16x4 p = *(const f16x4*)(Q + (size_t)kz * partStride + (size_t)r * ldq + c0);
#pragma unroll
    for (int k = 0; k < 4; k++) v[k] += (float)p[k];
  }
  float* o = out + (size_t)r * Ncols;
  if (c0 + 3 < Ncols) {
    *(float4*)(o + c0) = make_float4(v[0], v[1], v[2], v[3]);
  } else {
#pragma unroll
    for (int k = 0; k < 4; k++)
      if (c0 + k < Ncols) o[c0 + k] = v[k];
  }
}

// ---------------------------------------------------------------------------
// Launch
// ---------------------------------------------------------------------------
extern "C" void kernel_launch(void* const* d_in, const int* in_sizes, int n_in,
                              void* d_out, int out_size, void* d_ws, size_t ws_size,
                              hipStream_t stream) {
  const float* z = (const float*)d_in[0];
  const float* W = (const float*)d_in[1];
  const int* Kp = (const int*)d_in[2];

  const int D = D_DIM;
  const int B = in_sizes[0] / D;   // 4096
  const int C = in_sizes[1] / D;   // 1000
  const int Nsup = C + B;          // 5096
  const int Mpad = (Nsup + TM - 1) / TM * TM;  // 5120
  const int Npad = (C + TN - 1) / TN * TN;     // 1024

  char* ws = (char*)d_ws;
  size_t off = 0;
  auto alloc = [&](size_t bytes) -> void* {
    void* p = ws + off;
    off += (bytes + 255) & ~(size_t)255;
    return p;
  };

  const long pStride1 = (long)Mpad * Npad;   // f16 elems per partial (gemm1)
  const long pStride2 = (long)B * Npad;      // f16 elems per partial (gemm2)

  f16*   suph  = (f16*)alloc((size_t)Mpad * D * sizeof(f16));            // ~21.0 MB
  f16*   wh    = (f16*)alloc((size_t)Npad * D * sizeof(f16));            // ~4.2 MB
  f16*   P     = (f16*)alloc((size_t)SPLITK * pStride1 * sizeof(f16));   // ~41.9 MB
  float* ent   = (float*)alloc((size_t)Nsup * sizeof(float));
  int*   yhat  = (int*)alloc((size_t)Nsup * sizeof(int));
  float* norms = (float*)alloc((size_t)Nsup * sizeof(float));
  f16*   Q     = P;  // reuse: P fully consumed by row_stats before gemm2 writes Q
  (void)ws_size;

  // 1) f16 support matrix (padded) + norms
  prep_kernel<<<Mpad / 4, 256, 0, stream>>>(z, W, C, Nsup, suph, norms);

  // 2) logit partials: P[kz] = f16(supports @ W^T over K-quarter kz) (1280 blocks)
  {
    dim3 grid(Mpad / TM, Npad / TN, SPLITK);
    gemm_f16<<<grid, 256, 0, stream>>>(suph, suph, P, D, D / SPLITK, pStride1, Npad);
  }

  // 3) block-per-row split-K merge + argmax/entropy + exact ambiguity repair
  row_stats<<<Nsup, 256, 0, stream>>>(P, pStride1, Npad, C, z, W, ent, yhat);

  // 4) per-class gather/select/accumulate/normalize -> wh[Npad, D] f16
  accum_kernel<<<Npad, 256, 0, stream>>>(z, W, C, Nsup, yhat, ent, norms, Kp, wh);

  // 5) output partials: Q[kz] = f16(z @ weights^T over K-quarter kz) (1024 blocks)
  {
    dim3 grid(B / TM, Npad / TN, SPLITK);
    gemm_f16<<<grid, 256, 0, stream>>>(suph + (size_t)C * D, wh, Q, D, D / SPLITK,
                                       pStride2, Npad);
  }

  // 6) out = sum of 4 f16 partials (valid C cols only)
  reduce_out<<<B, 256, 0, stream>>>(Q, pStride2, Npad, (float*)d_out, C);
}

// Round 9
// 184.084 us; speedup vs baseline: 1.0954x; 1.0954x over previous
//
#include <hip/hip_runtime.h>
#include <math.h>

// Problem shape (from reference setup_inputs): B=4096, D=2048, C=1000, N=C+B=5096.
#define D_DIM 2048
// |approx_logit - exact_logit| bound: fp16-MFMA dot (~0.013) + 2x f16 partial
// roundings (~0.004). Candidate containment needs GAP_TAU >= true bound.
#define GAP_TAU 0.03f
#define SPLITK 2

typedef _Float16 f16;
typedef f16 f16x8 __attribute__((ext_vector_type(8)));
typedef f16 f16x4 __attribute__((ext_vector_type(4)));
typedef float f32x4 __attribute__((ext_vector_type(4)));

__device__ __forceinline__ const float* support_row(int i, const float* __restrict__ W,
                                                    const float* __restrict__ z, int C) {
  return (i < C) ? (W + (size_t)i * D_DIM) : (z + (size_t)(i - C) * D_DIM);
}

// async global->LDS, 16B per lane. LDS dest = wave-uniform base + lane*16.
__device__ __forceinline__ void async_ld16(const f16* g, f16* l) {
  __builtin_amdgcn_global_load_lds((const __attribute__((address_space(1))) void*)g,
                                   (__attribute__((address_space(3))) void*)l, 16, 0, 0);
}

// ---------------------------------------------------------------------------
// prep: suph[i][:] = f16(support_row(i)) (zeros for pad rows); norms[i] = ||row||.
// One wave per row (4 rows/block), shuffle-only reduction.
// ---------------------------------------------------------------------------
__global__ __launch_bounds__(256) void prep_kernel(const float* __restrict__ z,
                                                   const float* __restrict__ W,
                                                   int C, int Nsup,
                                                   f16* __restrict__ suph,
                                                   float* __restrict__ norms) {
  const int wave = threadIdx.x >> 6;
  const int lane = threadIdx.x & 63;
  const int i = blockIdx.x * 4 + wave;
  f16* dst = suph + (size_t)i * D_DIM;
  if (i >= Nsup) {
    f16x8 zz = {0, 0, 0, 0, 0, 0, 0, 0};
#pragma unroll
    for (int p = 0; p < 4; p++) *(f16x8*)(dst + p * 512 + lane * 8) = zz;
    return;
  }
  const float* src = support_row(i, W, z, C);
  float ss = 0.f;
#pragma unroll
  for (int p = 0; p < 4; p++) {
    const int off = p * 512 + lane * 8;
    const float4 a = *(const float4*)(src + off);
    const float4 b = *(const float4*)(src + off + 4);
    f16x8 v;
    v[0] = (f16)a.x; v[1] = (f16)a.y; v[2] = (f16)a.z; v[3] = (f16)a.w;
    v[4] = (f16)b.x; v[5] = (f16)b.y; v[6] = (f16)b.z; v[7] = (f16)b.w;
    *(f16x8*)(dst + off) = v;
    ss = fmaf(a.x, a.x, ss); ss = fmaf(a.y, a.y, ss);
    ss = fmaf(a.z, a.z, ss); ss = fmaf(a.w, a.w, ss);
    ss = fmaf(b.x, b.x, ss); ss = fmaf(b.y, b.y, ss);
    ss = fmaf(b.z, b.z, ss); ss = fmaf(b.w, b.w, ss);
  }
#pragma unroll
  for (int s = 1; s < 64; s <<= 1) ss += __shfl_xor(ss, s);
  if (lane == 0) norms[i] = sqrtf(ss);
}

// ---------------------------------------------------------------------------
// fp16 MFMA GEMM, split-K=2, f16 partials, BK=64, XCD-pinned work mapping.
// 1D grid, linear id l: xcd = l%8 owns A-row-groups tx = xcd + 8*(slot%txPerXcd)
// so each XCD's L2 keeps its A slice (~2.6 MB) + B (~4.2 MB) resident —
// tile refetch served from L2 instead of L3 (round-8 diagnosis: GEMM was
// L3-refetch bound at ~8 TB/s, 336 MB of tile traffic).
// 128x128 tile, 256 thr = 4 waves (2x2), wave = 64x64 = 4x4 MFMA 16x16x32,
// 2 k-steps per BK=64 iter (16 iters at Ks=1024 -> half the barriers of BK=32).
// LDS 32 KB. Swizzle: physical chunk p = g ^ (row&7); 8-lane groups span 8
// distinct chunks -> conflict-free ds_read_b128; staging lane-sequential.
// A/B padded to x128 rows; stores unpredicated into padded partial buffers.
// ---------------------------------------------------------------------------
#define TM 128
#define TN 128
#define BK 64

__global__ __launch_bounds__(256) void gemm_f16(const f16* __restrict__ A,
                                                const f16* __restrict__ B,
                                                f16* __restrict__ P,
                                                int K, int Ks, long partStride, int ldc,
                                                int txPerXcd) {
  __shared__ __align__(16) f16 As[TM * BK];  // 16 KB
  __shared__ __align__(16) f16 Bs[TN * BK];  // 16 KB

  const int l = blockIdx.x;
  const int xcd = l & 7;
  const int slot = l >> 3;
  const int tx = xcd + 8 * (slot % txPerXcd);
  const int rest = slot / txPerXcd;        // 0..15
  const int ty = rest & 7;
  const int kz = rest >> 3;
  const int row0 = tx * TM;
  const int col0 = ty * TN;
  const int kbase = kz * Ks;

  const int tid = threadIdx.x;
  const int wave = tid >> 6;
  const int lane = tid & 63;
  const int quad = lane >> 4;
  const int lr = lane & 15;
  const int wr = (wave >> 1) * 64;
  const int wc = (wave & 1) * 64;

  // staging: 1024 16B-chunks per tile -> 4 instr/thread for A, 4 for B.
  // chunk id i = (row<<3)|p; source global chunk g = p ^ (row&7).
  const f16* ag[4];
  const f16* bg[4];
  f16* al[4];
  f16* bl[4];
#pragma unroll
  for (int s = 0; s < 4; s++) {
    const int i = (wave * 4 + s) * 64 + lane;   // == LDS chunk id (staging contract)
    const int row = i >> 3;
    const int cg = (i & 7) ^ (row & 7);
    ag[s] = A + (size_t)(row0 + row) * K + kbase + cg * 8;
    bg[s] = B + (size_t)(col0 + row) * K + kbase + cg * 8;
    al[s] = As + (wave * 4 + s) * 512;
    bl[s] = Bs + (wave * 4 + s) * 512;
  }

  // fragment offsets: global chunk (s*4+quad) of row ra at physical
  // chunk ((s*4+quad) ^ (ra&7))
  int aoff[4][2], boff[4][2];
#pragma unroll
  for (int tq = 0; tq < 4; tq++) {
#pragma unroll
    for (int s = 0; s < 2; s++) {
      const int ra = wr + tq * 16 + lr;
      aoff[tq][s] = ra * 64 + (((s * 4 + quad) ^ (ra & 7)) << 3);
      const int rb = wc + tq * 16 + lr;
      boff[tq][s] = rb * 64 + (((s * 4 + quad) ^ (rb & 7)) << 3);
    }
  }

  f32x4 acc[4][4];
#pragma unroll
  for (int i = 0; i < 4; i++)
#pragma unroll
    for (int j = 0; j < 4; j++) {
      acc[i][j][0] = 0.f; acc[i][j][1] = 0.f; acc[i][j][2] = 0.f; acc[i][j][3] = 0.f;
    }

  for (int k0 = 0; k0 < Ks; k0 += BK) {
#pragma unroll
    for (int s = 0; s < 4; s++) {
      async_ld16(ag[s] + k0, al[s]);
      async_ld16(bg[s] + k0, bl[s]);
    }
    __syncthreads();

#pragma unroll
    for (int s = 0; s < 2; s++) {
      f16x8 af[4], bf[4];
#pragma unroll
      for (int i = 0; i < 4; i++) af[i] = *(const f16x8*)(As + aoff[i][s]);
#pragma unroll
      for (int i = 0; i < 4; i++) bf[i] = *(const f16x8*)(Bs + boff[i][s]);
#pragma unroll
      for (int i = 0; i < 4; i++)
#pragma unroll
        for (int j = 0; j < 4; j++)
          acc[i][j] = __builtin_amdgcn_mfma_f32_16x16x32_f16(af[i], bf[j], acc[i][j], 0, 0, 0);
    }
    __syncthreads();
  }

  f16* out = P + (size_t)kz * partStride;
#pragma unroll
  for (int i = 0; i < 4; i++)
#pragma unroll
    for (int reg = 0; reg < 4; reg++) {
      const int r = row0 + wr + i * 16 + quad * 4 + reg;
#pragma unroll
      for (int j = 0; j < 4; j++) {
        const int c = col0 + wc + j * 16 + lr;
        out[(size_t)r * ldc + c] = (f16)acc[i][j][reg];
      }
    }
}

// ---------------------------------------------------------------------------
// row_stats (block-per-row): logits row = sum of 2 f16 partials, read as one
// coalesced f16x4 (8B) per partial per thread (thread t owns cols t*4..+3).
// Argmax (lowest-index ties) + top-2 gap + entropy; ambiguous rows
// (gap <= 2*TAU) repaired with exact fp32 dots over candidate classes.
// ---------------------------------------------------------------------------
__global__ __launch_bounds__(256) void row_stats(const f16* __restrict__ P,
                                                 long partStride, int ldp, int Cc,
                                                 const float* __restrict__ z,
                                                 const float* __restrict__ W,
                                                 float* __restrict__ ent,
                                                 int* __restrict__ yhat) {
  const int r = blockIdx.x;
  const int t = threadIdx.x;
  const int wave = t >> 6;
  const int lane = t & 63;
  const int c0 = t * 4;

  float v[4] = {0.f, 0.f, 0.f, 0.f};
#pragma unroll
  for (int kz = 0; kz < SPLITK; kz++) {
    const f16x4 p = *(const f16x4*)(P + (size_t)kz * partStride + (size_t)r * ldp + c0);
#pragma unroll
    for (int k = 0; k < 4; k++) v[k] += (float)p[k];
  }
#pragma unroll
  for (int k = 0; k < 4; k++)
    if (c0 + k >= Cc) v[k] = -3.0e38f;

  // per-thread top-2 (+ lowest argmax idx; ascending k -> first hit wins)
  float m1 = -3.0e38f, m2 = -3.0e38f;
  int i1 = 0x7fffffff;
#pragma unroll
  for (int k = 0; k < 4; k++) {
    if (v[k] > m1) { m2 = m1; m1 = v[k]; i1 = c0 + k; }
    else if (v[k] > m2) { m2 = v[k]; }   // v[k]==m1 lands here -> m2=m1 (gap 0)
  }
  // wave merge
#pragma unroll
  for (int s = 1; s < 64; s <<= 1) {
    const float om1 = __shfl_xor(m1, s);
    const float om2 = __shfl_xor(m2, s);
    const int oi1 = __shfl_xor(i1, s);
    if (om1 > m1) { m2 = fmaxf(m1, om2); m1 = om1; i1 = oi1; }
    else if (om1 < m1) { m2 = fmaxf(m2, om1); }
    else { i1 = min(i1, oi1); m2 = m1; }
  }
  // cross-wave merge via LDS
  __shared__ float sm1[4], sm2[4];
  __shared__ int si[4];
  __shared__ float bc[4];   // M1, M2, S1, S2
  __shared__ int bidx;
  if (lane == 0) { sm1[wave] = m1; sm2[wave] = m2; si[wave] = i1; }
  __syncthreads();
  if (t == 0) {
    float M1 = sm1[0], M2 = sm2[0];
    int I = si[0];
#pragma unroll
    for (int w = 1; w < 4; w++) {
      const float o1 = sm1[w], o2 = sm2[w];
      const int oi = si[w];
      if (o1 > M1) { M2 = fmaxf(M1, o2); M1 = o1; I = oi; }
      else if (o1 < M1) { M2 = fmaxf(M2, o1); }
      else { I = min(I, oi); M2 = M1; }
    }
    bc[0] = M1; bc[1] = M2; bidx = I;
  }
  __syncthreads();
  const float M1 = bc[0];
  const float M2 = bc[1];
  int I1 = bidx;

  // entropy sums rel. M1 (consumed only if a class exceeds K members)
  float s1 = 0.f, s2 = 0.f;
#pragma unroll
  for (int k = 0; k < 4; k++) {
    if (c0 + k < Cc) {
      const float d = v[k] - M1;
      const float e = __expf(d);
      s1 += e;
      s2 = fmaf(d, e, s2);
    }
  }
#pragma unroll
  for (int s = 1; s < 64; s <<= 1) {
    s1 += __shfl_xor(s1, s);
    s2 += __shfl_xor(s2, s);
  }
  if (lane == 0) { sm1[wave] = s1; sm2[wave] = s2; }
  __syncthreads();
  if (t == 0) {
    bc[2] = sm1[0] + sm1[1] + sm1[2] + sm1[3];
    bc[3] = sm2[0] + sm2[1] + sm2[2] + sm2[3];
  }

  // ambiguous-argmax repair with exact fp32 dots (~8% of rows at tau=0.03)
  if (M1 - M2 <= 2.0f * GAP_TAU) {
    __shared__ int cand[64];
    __shared__ int ncand;
    __shared__ float red[256];
    if (t == 0) ncand = 0;
    __syncthreads();
    const float thresh = M1 - 2.0f * GAP_TAU;
#pragma unroll
    for (int k = 0; k < 4; k++) {
      if (c0 + k < Cc && v[k] >= thresh) {
        const int p = atomicAdd(&ncand, 1);
        if (p < 64) cand[p] = c0 + k;
      }
    }
    __syncthreads();
    const bool overflow = (ncand > 64);
    const int nc = overflow ? Cc : ncand;
    const float* srow = support_row(r, W, z, Cc);
    float best = -3.0e38f;
    int bi = 0x7fffffff;
    for (int j = 0; j < nc; j++) {
      const int c = overflow ? j : cand[j];
      const float* wrow = W + (size_t)c * D_DIM;
      float s = 0.f;
      for (int d = t; d < D_DIM; d += 256) s = fmaf(srow[d], wrow[d], s);
      red[t] = s;
      __syncthreads();
      for (int k = 128; k > 0; k >>= 1) {
        if (t < k) red[t] += red[t + k];
        __syncthreads();
      }
      const float val = red[0];
      __syncthreads();
      if (val > best || (val == best && c < bi)) { best = val; bi = c; }
    }
    I1 = bi;
  }
  __syncthreads();

  if (t == 0) {
    const float S1 = bc[2], S2 = bc[3];
    ent[r] = logf(S1) - S2 / S1;
    yhat[r] = I1;
  }
}

// ---------------------------------------------------------------------------
// accum: per class — gather members into LDS, top-K by entropy if count > K
// (never in practice: mean ~5, K=100), sum normalized rows, column-normalize,
// write f16 weights row. Pad classes write zeros. Thread t owns dims t*8..+7.
// ---------------------------------------------------------------------------
#define MAXLIST 1024

__global__ __launch_bounds__(256) void accum_kernel(const float* __restrict__ z,
                                                    const float* __restrict__ W,
                                                    int C, int Nsup,
                                                    const int* __restrict__ yhat,
                                                    const float* __restrict__ ent,
                                                    const float* __restrict__ norms,
                                                    const int* __restrict__ Kp,
                                                    f16* __restrict__ wh) {
  const int c = blockIdx.x;
  const int t = threadIdx.x;
  f16* dst = wh + (size_t)c * D_DIM + t * 8;
  if (c >= C) {
    f16x8 zz = {0, 0, 0, 0, 0, 0, 0, 0};
    *(f16x8*)dst = zz;
    return;
  }

  __shared__ int list[MAXLIST];
  __shared__ unsigned char sel[MAXLIST];
  __shared__ int cnt;
  __shared__ float red[256];
  if (t == 0) cnt = 0;
  __syncthreads();
  for (int i = t; i < Nsup; i += 256) {
    if (yhat[i] == c) {
      const int p = atomicAdd(&cnt, 1);
      if (p < MAXLIST) list[p] = i;
    }
  }
  __syncthreads();
  const int K = *Kp;
  const int n = min(cnt, MAXLIST);
  if (cnt <= K) {
    for (int j = t; j < n; j += 256) sel[j] = 1;
  } else {
    for (int j = t; j < n; j += 256) {
      const int si = list[j];
      const float ei = ent[si];
      int rank = 0;
      for (int l = 0; l < n; l++) {
        const int sl = list[l];
        const float el = ent[sl];
        rank += (el < ei || (el == ei && sl < si)) ? 1 : 0;
      }
      sel[j] = (rank < K) ? 1 : 0;
    }
  }
  __syncthreads();

  float a[8];
#pragma unroll
  for (int q = 0; q < 8; q++) a[q] = 0.f;
  for (int j = 0; j < n; j++) {
    if (!sel[j]) continue;
    const int si = list[j];
    const float* row = support_row(si, W, z, C) + t * 8;
    const float inv = 1.0f / fmaxf(norms[si], 1e-12f);
    const float4 p0 = *(const float4*)row;
    const float4 p1 = *(const float4*)(row + 4);
    a[0] = fmaf(p0.x, inv, a[0]); a[1] = fmaf(p0.y, inv, a[1]);
    a[2] = fmaf(p0.z, inv, a[2]); a[3] = fmaf(p0.w, inv, a[3]);
    a[4] = fmaf(p1.x, inv, a[4]); a[5] = fmaf(p1.y, inv, a[5]);
    a[6] = fmaf(p1.z, inv, a[6]); a[7] = fmaf(p1.w, inv, a[7]);
  }

  float ss = 0.f;
#pragma unroll
  for (int q = 0; q < 8; q++) ss = fmaf(a[q], a[q], ss);
  red[t] = ss;
  __syncthreads();
  for (int k = 128; k > 0; k >>= 1) {
    if (t < k) red[t] += red[t + k];
    __syncthreads();
  }
  const float invn = 1.0f / fmaxf(sqrtf(red[0]), 1e-12f);
  f16x8 o;
#pragma unroll
  for (int q = 0; q < 8; q++) o[q] = (f16)(a[q] * invn);
  *(f16x8*)dst = o;
}

// ---------------------------------------------------------------------------
// reduce_out: out[r][c] = sum of 2 f16 partials, c < Ncols. One block per
// row; thread t owns cols t*4..t*4+3 (coalesced f16x4 loads, float4 store).
// ---------------------------------------------------------------------------
__global__ __launch_bounds__(256) void reduce_out(const f16* __restrict__ Q,
                                                  long partStride, int ldq,
                                                  float* __restrict__ out, int Ncols) {
  const int r = blockIdx.x;
  const int c0 = threadIdx.x * 4;
  float v[4] = {0.f, 0.f, 0.f, 0.f};
#pragma unroll
  for (int kz = 0; kz < SPLITK; kz++) {
    const f16x4 p = *(const f16x4*)(Q + (size_t)kz * partStride + (size_t)r * ldq + c0);
#pragma unroll
    for (int k = 0; k < 4; k++) v[k] += (float)p[k];
  }
  float* o = out + (size_t)r * Ncols;
  if (c0 + 3 < Ncols) {
    *(float4*)(o + c0) = make_float4(v[0], v[1], v[2], v[3]);
  } else {
#pragma unroll
    for (int k = 0; k < 4; k++)
      if (c0 + k < Ncols) o[c0 + k] = v[k];
  }
}

// ---------------------------------------------------------------------------
// Launch
// ---------------------------------------------------------------------------
extern "C" void kernel_launch(void* const* d_in, const int* in_sizes, int n_in,
                              void* d_out, int out_size, void* d_ws, size_t ws_size,
                              hipStream_t stream) {
  const float* z = (const float*)d_in[0];
  const float* W = (const float*)d_in[1];
  const int* Kp = (const int*)d_in[2];

  const int D = D_DIM;
  const int B = in_sizes[0] / D;   // 4096
  const int C = in_sizes[1] / D;   // 1000
  const int Nsup = C + B;          // 5096
  const int Mpad = (Nsup + TM - 1) / TM * TM;  // 5120
  const int Npad = (C + TN - 1) / TN * TN;     // 1024

  char* ws = (char*)d_ws;
  size_t off = 0;
  auto alloc = [&](size_t bytes) -> void* {
    void* p = ws + off;
    off += (bytes + 255) & ~(size_t)255;
    return p;
  };

  const long pStride1 = (long)Mpad * Npad;   // f16 elems per partial (gemm1)
  const long pStride2 = (long)B * Npad;      // f16 elems per partial (gemm2)

  f16*   suph  = (f16*)alloc((size_t)Mpad * D * sizeof(f16));            // ~21.0 MB
  f16*   wh    = (f16*)alloc((size_t)Npad * D * sizeof(f16));            // ~4.2 MB
  f16*   P     = (f16*)alloc((size_t)SPLITK * pStride1 * sizeof(f16));   // ~21.0 MB
  float* ent   = (float*)alloc((size_t)Nsup * sizeof(float));
  int*   yhat  = (int*)alloc((size_t)Nsup * sizeof(int));
  float* norms = (float*)alloc((size_t)Nsup * sizeof(float));
  f16*   Q     = P;  // reuse: P fully consumed by row_stats before gemm2 writes Q
  (void)ws_size;

  // 1) f16 support matrix (padded) + norms
  prep_kernel<<<Mpad / 4, 256, 0, stream>>>(z, W, C, Nsup, suph, norms);

  // 2) logit partials: P[kz] = f16(supports @ W^T over K-half kz)
  //    1D grid 640 = 8 xcd * 5 txPerXcd * 8 ty * 2 kz (XCD-pinned mapping)
  {
    const int txPerXcd = (Mpad / TM) / 8;   // 5
    gemm_f16<<<640, 256, 0, stream>>>(suph, suph, P, D, D / SPLITK, pStride1, Npad,
                                      txPerXcd);
  }

  // 3) block-per-row split-K merge + argmax/entropy + exact ambiguity repair
  row_stats<<<Nsup, 256, 0, stream>>>(P, pStride1, Npad, C, z, W, ent, yhat);

  // 4) per-class gather/select/accumulate/normalize -> wh[Npad, D] f16
  accum_kernel<<<Npad, 256, 0, stream>>>(z, W, C, Nsup, yhat, ent, norms, Kp, wh);

  // 5) output partials: Q[kz] = f16(z @ weights^T over K-half kz)
  //    1D grid 512 = 8 * 4 * 8 * 2
  {
    const int txPerXcd = (B / TM) / 8;      // 4
    gemm_f16<<<512, 256, 0, stream>>>(suph + (size_t)C * D, wh, Q, D, D / SPLITK,
                                      pStride2, Npad, txPerXcd);
  }

  // 6) out = sum of 2 f16 partials (valid C cols only)
  reduce_out<<<B, 256, 0, stream>>>(Q, pStride2, Npad, (float*)d_out, C);
}